// Round 10
// baseline (404.584 us; speedup 1.0000x reference)
//
#include <hip/hip_runtime.h>

#define BATCH 32
#define NLEN  1024
#define NUMV  (BATCH * NLEN)

typedef __attribute__((ext_vector_type(8))) short short8;
typedef __attribute__((ext_vector_type(4))) float f32x4;

__device__ inline unsigned short rne_bf16(float x) {
    union { float f; unsigned u; } a; a.f = x;
    return (unsigned short)((a.u + 0x7FFFu + ((a.u >> 16) & 1u)) >> 16);
}
// fp32 -> bf16 hi + bf16 lo (both RNE): x ~= hi + lo, rel err ~2^-17
__device__ inline void bsplit(float x, unsigned short& h, unsigned short& l) {
    union { float f; unsigned u; } a; a.f = x;
    unsigned hb = (a.u + 0x7FFFu + ((a.u >> 16) & 1u)) & 0xFFFF0000u;
    h = (unsigned short)(hb >> 16);
    union { unsigned u; float f; } hf; hf.u = hb;
    l = rne_bf16(x - hf.f);
}
__device__ inline float bf16_to_f(unsigned short v) {
    union { unsigned u; float f; } a; a.u = ((unsigned)v) << 16; return a.f;
}

template<int N> __device__ __forceinline__ void wait_vmcnt() {
    if constexpr (N == 0)      asm volatile("s_waitcnt vmcnt(0)" ::: "memory");
    else if constexpr (N == 1) asm volatile("s_waitcnt vmcnt(1)" ::: "memory");
    else if constexpr (N == 2) asm volatile("s_waitcnt vmcnt(2)" ::: "memory");
    else static_assert(N <= 2, "");
}

// Packed layout per layer (bank-conflict-free transposed chunks):
//   f = ((nt*KC + kc)*2 + hl)*512 + g*128 + c*8 + j
//   -> W[k = kc*32+g*8+j][col = nt*16+c], W = [Wm | Ws], zero-pad k >= CIN.
// hl: 0 = hi bf16, 1 = lo bf16. One B tile (all kc, hi+lo) contiguous: KC*2KB.
template<int CIN, int COUT, int H>
__device__ void pack_layer(const float* __restrict__ Wm, const float* __restrict__ Ws,
                           unsigned short* __restrict__ out, int t0, int nthr)
{
    constexpr int HC = H * COUT;
    constexpr int KC = ((CIN + 31) & ~31) / 32;
    constexpr int NT = (HC + COUT) / 16;
    const int total = NT * KC * 1024;
    for (int f = t0; f < total; f += nthr) {
        int j  = f & 7;
        int c  = (f >> 3) & 15;
        int g  = (f >> 7) & 3;
        int hl = (f >> 9) & 1;
        int r2 = f >> 10;
        int kc = r2 % KC, nt = r2 / KC;
        int k = kc * 32 + g * 8 + j, col = nt * 16 + c;
        float v = 0.f;
        if (k < CIN) v = (col < HC) ? Wm[k * HC + col] : Ws[k * COUT + (col - HC)];
        unsigned short h, l; bsplit(v, h, l);
        out[f] = hl ? l : h;
    }
}

__global__ void pack_all(const float* Wm1, const float* Ws1, const float* Wm2, const float* Ws2,
                         const float* Wm3, const float* Ws3, const float* Wm4, const float* Ws4,
                         unsigned short* p1, unsigned short* p2, unsigned short* p3, unsigned short* p4)
{
    int t = blockIdx.x * 256 + threadIdx.x;
    int n = gridDim.x * 256;
    pack_layer<1, 128, 8>(Wm1, Ws1, p1, t, n);
    pack_layer<128, 128, 8>(Wm2, Ws2, p2, t, n);
    pack_layer<128, 64, 16>(Wm3, Ws3, p3, t, n);
    pack_layer<64, 64, 16>(Wm4, Ws4, p4, t, n);
}

// Fused GeneralConv layer. r4 structure + params-in-LDS + 2-deep reg staging
// with counted vmcnt across raw barriers (no full drains in steady state).
// Block = 4 waves x 16 rows (14 useful) = 56 rows; grid = 32*19 = 608 blocks.
// Weights via plain loads (L2-resident; NO global_load_lds per r7 lesson).
template<int CIN, int COUT, int H, bool MPACK>
__global__ __launch_bounds__(256, 2)
void conv_reg(const float* __restrict__ x, const unsigned short* __restrict__ pw,
              const float* __restrict__ bm, const float* __restrict__ bs,
              const float* __restrict__ att, float* __restrict__ y)
{
    constexpr int HC = H * COUT;
    static_assert(HC == 1024, "");
    constexpr int KC   = ((CIN + 31) & ~31) / 32;
    constexpr int HT   = COUT / 16;          // tiles per head == self tiles (even)
    constexpr int MT   = HC / 16;            // 64 message tiles (even)
    constexpr int NTOT = MT + HT;
    constexpr int NCH  = KC * 128;           // 16B chunks per B tile
    constexpr int CHPT = (NCH + 255) / 256;  // chunks per thread (1 or 2)
    constexpr int ROWSB = 56;
    constexpr int TPG  = (NLEN + ROWSB - 1) / ROWSB;  // 19
    constexpr int PL   = HC + COUT;
    constexpr float invH = 1.0f / H;

    const int tid  = threadIdx.x;
    const int lane = tid & 63;
    const int w    = tid >> 6;                // wave 0..3
    const int r    = lane & 15;               // A row in set / B col / C col
    const int gg   = lane >> 4;               // k-group; C row = gg*4+e
    const int g    = blockIdx.x / TPG;
    const int n0   = (blockIdx.x % TPG) * ROWSB;
    const size_t gstart = (size_t)g * NLEN;

    __shared__ alignas(16) unsigned short bufs[2][KC * 1024];
    __shared__ alignas(8) float pl[PL * 2];   // (bm,att) msg cols; (bs,-) self cols

    // ---- params -> LDS ----
    for (int i = tid; i < PL; i += 256) {
        float a, b;
        if (i < HC) { a = bm[i]; b = att[i]; }
        else        { a = bs[i - HC]; b = 0.f; }
        pl[2 * i] = a; pl[2 * i + 1] = b;
    }

    // ---- A fragments (one row-set, built once from global; fully consumed here) ----
    short8 a_hi[KC], a_lo[KC];
    {
        const int na = n0 - 1 + w * 14 + r;          // within-graph node of A row
        const bool av = (na >= 0) && (na < NLEN);
        const float* xrow = x + (gstart + (size_t)(av ? na : 0)) * CIN;
        #pragma unroll
        for (int kc = 0; kc < KC; kc++) {
            float vals[8];
            if constexpr (CIN % 32 == 0) {
                if (av) {
                    f32x4 v0 = *(const f32x4*)(xrow + kc * 32 + gg * 8);
                    f32x4 v1 = *(const f32x4*)(xrow + kc * 32 + gg * 8 + 4);
                    vals[0]=v0[0]; vals[1]=v0[1]; vals[2]=v0[2]; vals[3]=v0[3];
                    vals[4]=v1[0]; vals[5]=v1[1]; vals[6]=v1[2]; vals[7]=v1[3];
                } else {
                    #pragma unroll
                    for (int jj = 0; jj < 8; jj++) vals[jj] = 0.f;
                }
            } else {
                #pragma unroll
                for (int jj = 0; jj < 8; jj++) {
                    int k = kc * 32 + gg * 8 + jj;
                    vals[jj] = (av && k < CIN) ? xrow[k] : 0.f;
                }
            }
            union { short8 v; unsigned short u[8]; } hu, lu;
            #pragma unroll
            for (int jj = 0; jj < 8; jj++) bsplit(vals[jj], hu.u[jj], lu.u[jj]);
            a_hi[kc] = hu.v; a_lo[kc] = lu.v;
        }
    }

    float out[HT][4];
    #pragma unroll
    for (int q = 0; q < HT; q++)
        #pragma unroll
        for (int e = 0; e < 4; e++) out[q][e] = 0.f;

    float    mf[MPACK ? 1 : HT][4];      // per-head messages, f32 variant
    unsigned mpk[MPACK ? HT : 1][2];     // per-head messages, bf16x2 variant

    const int boff = gg * 128 + r * 8;   // transposed-chunk read offset (conflict-free)

    f32x4 sA[CHPT], sB[CHPT];

    auto issueLoads = [&](f32x4 (&s)[CHPT], int nt) {
        const f32x4* ps = (const f32x4*)pw + (size_t)nt * NCH;
        #pragma unroll
        for (int i = 0; i < CHPT; i++) { int idx = tid + i * 256; if (idx < NCH) s[i] = ps[idx]; }
    };
    auto writeLds = [&](f32x4 (&s)[CHPT], int par) {
        #pragma unroll
        for (int i = 0; i < CHPT; i++) { int idx = tid + i * 256; if (idx < NCH) *(f32x4*)&bufs[par][idx * 8] = s[i]; }
    };
    auto fence = [&]() {                       // publish LDS writes, NO vmcnt drain
        asm volatile("s_waitcnt lgkmcnt(0)" ::: "memory");
        __builtin_amdgcn_sched_barrier(0);
        __builtin_amdgcn_s_barrier();
        __builtin_amdgcn_sched_barrier(0);
    };
    auto mfma2 = [&](int par, float seed) -> f32x4 {   // 2 independent chains
        short8 bh[KC], bl[KC];
        #pragma unroll
        for (int kc = 0; kc < KC; kc++) {
            bh[kc] = *(const short8*)&bufs[par][(kc * 2 + 0) * 512 + boff];
            bl[kc] = *(const short8*)&bufs[par][(kc * 2 + 1) * 512 + boff];
        }
        f32x4 acc0 = {seed, seed, seed, seed};
        f32x4 acc1 = {0.f, 0.f, 0.f, 0.f};
        #pragma unroll
        for (int kc = 0; kc < KC; kc++) {
            acc0 = __builtin_amdgcn_mfma_f32_16x16x32_bf16(a_hi[kc], bh[kc], acc0, 0, 0, 0);
            acc1 = __builtin_amdgcn_mfma_f32_16x16x32_bf16(a_hi[kc], bl[kc], acc1, 0, 0, 0);
            acc1 = __builtin_amdgcn_mfma_f32_16x16x32_bf16(a_lo[kc], bh[kc], acc1, 0, 0, 0);
        }
        return acc0 + acc1;
    };
    auto msgTile = [&](int q, int nt, int par, float (&p)[4]) {   // q compile-time
        const float2 pv = *(const float2*)&pl[(nt * 16 + r) * 2]; // (bm, att)
        f32x4 vv = mfma2(par, pv.x);
        #pragma unroll
        for (int e = 0; e < 4; e++) {
            float v = vv[e];
            v = v > 0.f ? v : 0.01f * v;     // leaky_relu(0.01)
            vv[e] = v;
            p[e] += v * pv.y;                // logit partial (col r)
        }
        if constexpr (MPACK) {
            mpk[q][0] = ((unsigned)rne_bf16(vv[1]) << 16) | rne_bf16(vv[0]);
            mpk[q][1] = ((unsigned)rne_bf16(vv[3]) << 16) | rne_bf16(vv[2]);
        } else {
            #pragma unroll
            for (int e = 0; e < 4; e++) mf[q][e] = vv[e];
        }
    };
    auto selfTile = [&](int q2, int par) {
        const int c2 = q2 * 16 + r;
        f32x4 acc = mfma2(par, pl[(HC + c2) * 2]);
        const int jbase = w * 14;
        #pragma unroll
        for (int e = 0; e < 4; e++) {
            const int jr = gg * 4 + e;
            const int nl = n0 - 1 + jbase + jr;
            float v = out[q2][e] * invH + acc[e];
            v = v > 0.f ? v : __expf(v) - 1.f;          // ELU (layers 1..4)
            if (jr >= 1 && jr <= 14 && nl < NLEN)
                y[(gstart + nl) * COUT + c2] = v;
        }
    };

    // ---- pipeline prologue: tile0 -> LDS, tile1 in flight ----
    issueLoads(sA, 0);
    wait_vmcnt<0>();                 // drains everything (params consumed above)
    writeLds(sA, 0);
    issueLoads(sA, 1);
    fence();                         // tile0 visible; sA(tile1) stays in flight

    // ---- message tiles, per head (2 tiles per body, E/O reg sets) ----
    for (int h = 0; h < H; h++) {
        float p[4] = {0.f, 0.f, 0.f, 0.f};
        #pragma unroll
        for (int qq = 0; qq < HT; qq += 2) {
            const int nt = h * HT + qq;          // even -> par 0
            issueLoads(sB, nt + 2);              // always < NTOT in msg loop
            msgTile(qq, nt, 0, p);
            wait_vmcnt<CHPT>();                  // sA (tile nt+1) landed
            writeLds(sA, 1);
            fence();                             // tile nt+1 visible
            issueLoads(sA, nt + 3);              // always < NTOT in msg loop
            msgTile(qq + 1, nt + 1, 1, p);
            wait_vmcnt<CHPT>();                  // sB (tile nt+2) landed
            writeLds(sB, 0);
            fence();                             // tile nt+2 visible
        }
        // ---- logits: butterfly all-reduce over the 16 lanes of each row ----
        #pragma unroll
        for (int e = 0; e < 4; e++) {
            float v = p[e];
            v += __shfl_xor(v, 1, 64);
            v += __shfl_xor(v, 2, 64);
            v += __shfl_xor(v, 4, 64);
            v += __shfl_xor(v, 8, 64);
            p[e] = v;                                   // alpha[row gg*4+e]
        }
        // ---- softmax over <=2 incoming edges + aggregate into out regs ----
        {
            const int jbase = w * 14;
            float a3u = __shfl_up(p[3], 16, 64);        // alpha of row-1 for e==0
            float a0d = __shfl_down(p[0], 16, 64);      // alpha of row+1 for e==3
            float wpv[4], wnv[4];
            #pragma unroll
            for (int e = 0; e < 4; e++) {
                const int jr = gg * 4 + e;
                const int nl = n0 - 1 + jbase + jr;     // within-graph node idx
                const bool hp = nl >= 1;
                const bool hn = nl < NLEN - 1;
                float ap = (e > 0) ? p[e - 1] : a3u;
                float an = (e < 3) ? p[e + 1] : a0d;
                float apx = hp ? ap : -1e30f;
                float anx = hn ? an : -1e30f;
                float mx = fmaxf(apx, anx);
                float ep = hp ? __expf(ap - mx) : 0.f;
                float en = hn ? __expf(an - mx) : 0.f;
                float inv = 1.f / (ep + en + 1e-16f);
                wpv[e] = ep * inv; wnv[e] = en * inv;
            }
            #pragma unroll
            for (int q = 0; q < HT; q++) {
                float v0, v1, v2, v3;
                if constexpr (MPACK) {
                    v0 = bf16_to_f((unsigned short)(mpk[q][0] & 0xffff));
                    v1 = bf16_to_f((unsigned short)(mpk[q][0] >> 16));
                    v2 = bf16_to_f((unsigned short)(mpk[q][1] & 0xffff));
                    v3 = bf16_to_f((unsigned short)(mpk[q][1] >> 16));
                } else {
                    v0 = mf[q][0]; v1 = mf[q][1]; v2 = mf[q][2]; v3 = mf[q][3];
                }
                float m3u = __shfl_up(v3, 16, 64);      // M[row-1] for e==0
                float m0d = __shfl_down(v0, 16, 64);    // M[row+1] for e==3
                float mvals[4] = {v0, v1, v2, v3};
                #pragma unroll
                for (int e = 0; e < 4; e++) {
                    float mprev = (e > 0) ? mvals[e - 1] : m3u;
                    float mnext = (e < 3) ? mvals[e + 1] : m0d;
                    out[q][e] += wpv[e] * mprev + wnv[e] * mnext;
                }
            }
        }
    }

    // ---- self-loop tiles + finalize + store ----
    #pragma unroll
    for (int q2 = 0; q2 < HT; q2 += 2) {
        const int nt = MT + q2;                  // even -> par 0
        constexpr int dummy = 0; (void)dummy;
        const bool i1 = (nt + 2 < NTOT);         // compile-time after unroll
        const bool i2 = (nt + 3 < NTOT);
        if (i1) issueLoads(sB, nt + 2);
        selfTile(q2, 0);
        if (i1) wait_vmcnt<CHPT>(); else wait_vmcnt<0>();
        writeLds(sA, 1);                         // sA holds tile nt+1
        fence();
        if (i2) issueLoads(sA, nt + 3);
        selfTile(q2 + 1, 1);
        if (q2 + 2 < HT) {
            if (i2) wait_vmcnt<CHPT>(); else wait_vmcnt<0>();
            writeLds(sB, 0);                     // sB holds tile nt+2
            fence();
        }
    }
}

// Layer 5 + head at the last node per graph (single incoming edge -> softmax weight 1).
__global__ void final_head(const float* __restrict__ x4,   // [NUMV][64]
                           const float* __restrict__ Wm,   // [64][32]
                           const float* __restrict__ bm,
                           const float* __restrict__ Ws,   // [64][32]
                           const float* __restrict__ bs,
                           const float* __restrict__ Wc,   // [32][1]
                           const float* __restrict__ bc,
                           float* __restrict__ out)        // [32] ++ [32*32]
{
    int g = blockIdx.x;
    int c = threadIdx.x;
    const float* xu = &x4[((long)g * NLEN + NLEN - 2) * 64];
    const float* xv = xu + 64;
    float o = 0.f;
    if (c < 32) {
        float m = bm[c];
        float s = bs[c];
        for (int k = 0; k < 64; k++) {
            m = fmaf(xu[k], Wm[k * 32 + c], m);
            s = fmaf(xv[k], Ws[k * 32 + c], s);
        }
        m = m > 0.f ? m : 0.01f * m;
        o = m + s;
        out[32 + g * 32 + c] = o;
    }
    float tsum = (c < 32) ? o * Wc[c] : 0.f;
    #pragma unroll
    for (int sft = 16; sft > 0; sft >>= 1)
        tsum += __shfl_xor(tsum, sft, 64);
    if (c == 0) out[g] = tsum + bc[0];
}

extern "C" void kernel_launch(void* const* d_in, const int* in_sizes, int n_in,
                              void* d_out, int out_size, void* d_ws, size_t ws_size,
                              hipStream_t stream)
{
    const float* nodes = (const float*)d_in[0];
    auto L = [&](int l, int k) { return (const float*)d_in[1 + (l - 1) * 5 + k]; };

    float* xb0 = (float*)d_ws;                       // [NUMV][128] f32
    float* xb1 = xb0 + (size_t)NUMV * 128;
    unsigned short* p1 = (unsigned short*)(xb1 + (size_t)NUMV * 128);
    unsigned short* p2 = p1 + 72 * 1024;             // L1: NT=72, KC=1
    unsigned short* p3 = p2 + 72 * 4096;             // L2: NT=72, KC=4
    unsigned short* p4 = p3 + 68 * 4096;             // L3: NT=68, KC=4
                                                     // L4: NT=68, KC=2

    pack_all<<<dim3(512), dim3(256), 0, stream>>>(
        L(1,0), L(1,2), L(2,0), L(2,2), L(3,0), L(3,2), L(4,0), L(4,2), p1, p2, p3, p4);

    constexpr int TPG = (NLEN + 55) / 56;            // 19
    dim3 grid(BATCH * TPG);                          // 608 blocks
    dim3 blk(256);

    conv_reg<1,   128, 8,  false><<<grid, blk, 0, stream>>>(nodes, p1, L(1,1), L(1,3), L(1,4), xb0);
    conv_reg<128, 128, 8,  true ><<<grid, blk, 0, stream>>>(xb0,   p2, L(2,1), L(2,3), L(2,4), xb1);
    conv_reg<128, 64,  16, false><<<grid, blk, 0, stream>>>(xb1,   p3, L(3,1), L(3,3), L(3,4), xb0);
    conv_reg<64,  64,  16, false><<<grid, blk, 0, stream>>>(xb0,   p4, L(4,1), L(4,3), L(4,4), xb1);

    final_head<<<dim3(BATCH), dim3(64), 0, stream>>>(
        xb1, L(5,0), L(5,1), L(5,2), L(5,3),
        (const float*)d_in[26], (const float*)d_in[27], (float*)d_out);
}